// Round 8
// baseline (320.893 us; speedup 1.0000x reference)
//
#include <hip/hip_runtime.h>
#include <stdint.h>

typedef unsigned int  u32;
typedef unsigned short u16;
typedef __bf16 v8bf __attribute__((ext_vector_type(8)));
typedef float  v4f  __attribute__((ext_vector_type(4)));

#define N_INST 256
#define BATCH  128
#define IN_DIM 1024
#define L_DIM  512
#define M_TOT  (N_INST*BATCH)   // 32768
#define NSLICE 16               // 16 colslices (full K per block now)

// Fragment-tiled layouts (u16 units). Region = 1 KB = 64 lanes x 16 B.
// A (xb): region = mblk*256 + kt*16 + g*2 + kk   (g=row-group 0..7)
//   lane(q,c): row = mblk*128 + g*16 + c, k = kt*64 + kk*32 + q*8
// B (wpk): region = cs*128 + kt*8 + j*2 + kk     (cs=colslice 0..15, j=0..3)
//   lane(q,c): packed col p = cs*64 + j*16 + c, k = kt*64 + kk*32 + q*8
//   bcol = p>>4 = cs*4+j (even=V, odd=U), l = (bcol>>1)*16 + c
// ws: [0,64MB) xb; [64MB,66MB) wpk; [66MB,68MB) partial [16][M_TOT]
#define XB_BYTES   ((size_t)M_TOT * IN_DIM * 2)
#define WPK_BYTES  ((size_t)1024 * IN_DIM * 2)

__device__ inline u32 f2bf_pk(float a, float b){
  u32 ua = __builtin_bit_cast(u32, a);
  u32 ub = __builtin_bit_cast(u32, b);
  ua = (ua + 0x7FFFu + ((ua >> 16) & 1u)) >> 16;
  ub = (ub + 0x7FFFu + ((ub >> 16) & 1u)) & 0xFFFF0000u;
  return ua | ub;
}

__device__ inline void gl2lds16(const u16* g, u16* l){
  __builtin_amdgcn_global_load_lds(
      (const __attribute__((address_space(1))) u32*)(g),
      (__attribute__((address_space(3))) u32*)(l), 16, 0, 0);
}

#define PREP_XBLKS 16384
__global__ void prep(const float* __restrict__ x, const float* __restrict__ v,
                     const float* __restrict__ u, u16* __restrict__ xb,
                     u16* __restrict__ wpk){
  const int b = blockIdx.x;
  if (b < PREP_XBLKS){
    int t = b * 256 + threadIdx.x;
    int r = t >> 6, l = t & 63;
    int kk = r & 1, i = (r >> 1) & 3, h = (r >> 3) & 1, kt = (r >> 4) & 15, mb = r >> 8;
    int q = l >> 4, c = l & 15;
    int row = mb*128 + h*64 + i*16 + c;
    int k0  = kt*64 + kk*32 + q*8;
    const float* src = x + (size_t)row * IN_DIM + k0;
    float4 a0 = *reinterpret_cast<const float4*>(src);
    float4 a1 = *reinterpret_cast<const float4*>(src + 4);
    uint4 out;
    out.x = f2bf_pk(a0.x, a0.y); out.y = f2bf_pk(a0.z, a0.w);
    out.z = f2bf_pk(a1.x, a1.y); out.w = f2bf_pk(a1.z, a1.w);
    *reinterpret_cast<uint4*>(xb + (size_t)r*512 + l*8) = out;
  } else {
    int t = (b - PREP_XBLKS) * 256 + threadIdx.x;   // 131072 threads
    int r = t >> 6, l = t & 63;
    int kk = r & 1, j = (r >> 1) & 3, kt = (r >> 3) & 15, cs = r >> 7;
    int q = l >> 4, c = l & 15;
    int bcol = cs*4 + j;
    const float* src = (bcol & 1) ? u : v;
    int lcol = (bcol >> 1)*16 + c;
    int k0 = kt*64 + kk*32 + q*8;
    u32 o[4];
#pragma unroll
    for (int ii = 0; ii < 4; ++ii){
      float a  = src[(size_t)(k0 + 2*ii    ) * L_DIM + lcol];
      float bb = src[(size_t)(k0 + 2*ii + 1) * L_DIM + lcol];
      o[ii] = f2bf_pk(a, bb);
    }
    *reinterpret_cast<uint4*>(wpk + (size_t)r*512 + l*8) = make_uint4(o[0], o[1], o[2], o[3]);
  }
}

__launch_bounds__(256, 2)
__global__ void gemm_score(const u16* __restrict__ xb, const u16* __restrict__ wpk,
                           const float* __restrict__ w, float* __restrict__ partial){
  // Block = 4 mblk x 64 packed cols x FULL K (activation after complete sum).
  // B staged in two 64 KB K-halves; 3 barriers total; waves free-run otherwise.
  __shared__ __align__(16) u16 Bs[64 * 512];   // 64 KB -> 2 blocks/CU

  const int tid  = threadIdx.x;
  const u32 bid  = blockIdx.x;          // 0..1023
  const int xcd  = bid & 7;
  const int slot = bid >> 3;            // 0..127
  const int cs   = slot & 15;           // colslice
  const int mr   = xcd*8 + (slot >> 4); // mrange 0..63 (XCD-local A reuse in L2)
  const int mblk0= mr * 4;

  const int lane = tid & 63;
  const int wave = tid >> 6;
  const int q    = lane >> 4;
  const int c    = lane & 15;

  auto stageB = [&](int kh){
    const u16* src = wpk + (size_t)(cs*128 + kh*64) * 512;
#pragma unroll
    for (int it = 0; it < 16; ++it){
      const int rl = wave*16 + it;
      gl2lds16(src + (size_t)rl*512 + lane*8, &Bs[rl*512 + lane*8]);
    }
  };

  // wave owns rows wave*32..+31 of each mblk (row-groups g = 2*wave, 2*wave+1)
  const u16* awave = xb + (size_t)mblk0*131072 + (size_t)(2*wave)*1024 + lane*8;

  v4f acc[4][2][4];
#pragma unroll
  for (int mb = 0; mb < 4; ++mb)
#pragma unroll
    for (int gi = 0; gi < 2; ++gi)
#pragma unroll
      for (int j = 0; j < 4; ++j)
        acc[mb][gi][j] = (v4f){0.f, 0.f, 0.f, 0.f};

  stageB(0);
  __syncthreads();

#pragma unroll 1
  for (int kh = 0; kh < 2; ++kh){
#pragma unroll 1
    for (int ktl = 0; ktl < 8; ++ktl){
      const int kt = kh*8 + ktl;
      v8bf bfr[4][2];
#pragma unroll
      for (int j = 0; j < 4; ++j)
#pragma unroll
        for (int kk = 0; kk < 2; ++kk)
          bfr[j][kk] = *reinterpret_cast<const v8bf*>(&Bs[(ktl*8 + j*2 + kk)*512 + lane*8]);
      v8bf af[4][2][2];
      const u16* ak = awave + (size_t)kt * 8192;
#pragma unroll
      for (int mb = 0; mb < 4; ++mb)
#pragma unroll
        for (int gi = 0; gi < 2; ++gi)
#pragma unroll
          for (int kk = 0; kk < 2; ++kk)
            af[mb][gi][kk] = *reinterpret_cast<const v8bf*>(ak + mb*131072 + gi*1024 + kk*512);
#pragma unroll
      for (int mb = 0; mb < 4; ++mb)
#pragma unroll
        for (int kk = 0; kk < 2; ++kk)
#pragma unroll
          for (int gi = 0; gi < 2; ++gi)
#pragma unroll
            for (int j = 0; j < 4; ++j)
              acc[mb][gi][j] = __builtin_amdgcn_mfma_f32_16x16x32_bf16(
                  af[mb][gi][kk], bfr[j][kk], acc[mb][gi][j], 0, 0, 0);
    }
    if (kh == 0){
      __syncthreads();   // all waves done reading Bs half 0
      stageB(1);
      __syncthreads();   // half 1 visible
    }
  }

  // epilogue (full-K sums now): j pairs (0,1)=V,U @ l=cs*32+c ; (2,3) @ +16
  const float wl0 = w[cs*32 + c];
  const float wl1 = w[cs*32 + 16 + c];
  float* pbase = partial + (size_t)cs * M_TOT;

#pragma unroll
  for (int mb = 0; mb < 4; ++mb){
    float* pout = pbase + (size_t)(mblk0 + mb)*128 + wave*32;
#pragma unroll
    for (int gi = 0; gi < 2; ++gi){
#pragma unroll
      for (int r = 0; r < 4; ++r){
        float t0 = 2.f / (1.f + __expf(-2.f * acc[mb][gi][0][r])) - 1.f;
        float s0 = 1.f / (1.f + __expf(-acc[mb][gi][1][r]));
        float t1 = 2.f / (1.f + __expf(-2.f * acc[mb][gi][2][r])) - 1.f;
        float s1 = 1.f / (1.f + __expf(-acc[mb][gi][3][r]));
        float v2 = t0*s0*wl0 + t1*s1*wl1;
        v2 += __shfl_xor(v2, 1, 64);
        v2 += __shfl_xor(v2, 2, 64);
        v2 += __shfl_xor(v2, 4, 64);
        v2 += __shfl_xor(v2, 8, 64);
        if (c == 0) pout[gi*16 + q*4 + r] = v2;   // slice-private rows
      }
    }
  }
}

__global__ void softmax_inst(const float* __restrict__ partial, float* __restrict__ out){
  __shared__ float red[N_INST];
  const int b = blockIdx.x;
  const int n = threadIdx.x;
  float s = 0.f;
#pragma unroll
  for (int i = 0; i < NSLICE; ++i) s += partial[(size_t)i * M_TOT + n*BATCH + b];
  red[n] = s; __syncthreads();
  for (int st = N_INST/2; st > 0; st >>= 1){
    if (n < st) red[n] = fmaxf(red[n], red[n + st]);
    __syncthreads();
  }
  float mx = red[0]; __syncthreads();
  float e = __expf(s - mx);
  red[n] = e; __syncthreads();
  for (int st = N_INST/2; st > 0; st >>= 1){
    if (n < st) red[n] += red[n + st];
    __syncthreads();
  }
  out[n*BATCH + b] = e / red[0];
}

extern "C" void kernel_launch(void* const* d_in, const int* in_sizes, int n_in,
                              void* d_out, int out_size, void* d_ws, size_t ws_size,
                              hipStream_t stream) {
  const float* x = (const float*)d_in[0];
  const float* v = (const float*)d_in[1];
  const float* u = (const float*)d_in[2];
  const float* w = (const float*)d_in[3];
  u16*   xb      = (u16*)d_ws;
  u16*   wpk     = (u16*)((char*)d_ws + XB_BYTES);
  float* partial = (float*)((char*)d_ws + XB_BYTES + WPK_BYTES);
  float* out     = (float*)d_out;

  prep<<<dim3(PREP_XBLKS + 512), dim3(256), 0, stream>>>(x, v, u, xb, wpk);
  gemm_score<<<dim3(1024), dim3(256), 0, stream>>>(xb, wpk, w, partial);
  softmax_inst<<<dim3(BATCH), dim3(N_INST), 0, stream>>>(partial, out);
}

// Round 9
// 285.471 us; speedup vs baseline: 1.1241x; 1.1241x over previous
//
#include <hip/hip_runtime.h>
#include <stdint.h>

typedef unsigned int  u32;
typedef unsigned short u16;
typedef __bf16 v8bf __attribute__((ext_vector_type(8)));
typedef float  v4f  __attribute__((ext_vector_type(4)));

#define N_INST 256
#define BATCH  128
#define IN_DIM 1024
#define L_DIM  512
#define M_TOT  (N_INST*BATCH)   // 32768
#define NSLICE 16               // 16 colslices, full K per block

// Fragment-tiled layouts (u16 units). Region = 1 KB = 64 lanes x 16 B.
// A (xb): region = mblk*256 + kt*16 + g*2 + kk   (g=row-group 0..7)
//   lane(q,c): row = mblk*128 + g*16 + c, k = kt*64 + kk*32 + q*8
// B (wpk): region = cs*128 + kt*8 + j*2 + kk     (cs=colslice 0..15, j=0..3)
//   lane(q,c): packed col p = cs*64 + j*16 + c, k = kt*64 + kk*32 + q*8
//   bcol = p>>4 = cs*4+j (even=V, odd=U), l = (bcol>>1)*16 + c
// ws: [0,64MB) xb; [64MB,66MB) wpk; [66MB,68MB) partial [16][M_TOT]
#define XB_BYTES   ((size_t)M_TOT * IN_DIM * 2)
#define WPK_BYTES  ((size_t)1024 * IN_DIM * 2)

__device__ inline u32 f2bf_pk(float a, float b){
  u32 ua = __builtin_bit_cast(u32, a);
  u32 ub = __builtin_bit_cast(u32, b);
  ua = (ua + 0x7FFFu + ((ua >> 16) & 1u)) >> 16;
  ub = (ub + 0x7FFFu + ((ub >> 16) & 1u)) & 0xFFFF0000u;
  return ua | ub;
}

__device__ inline void gl2lds16(const u16* g, u16* l){
  __builtin_amdgcn_global_load_lds(
      (const __attribute__((address_space(1))) u32*)(g),
      (__attribute__((address_space(3))) u32*)(l), 16, 0, 0);
}

#define PREP_XBLKS 16384
__global__ void prep(const float* __restrict__ x, const float* __restrict__ v,
                     const float* __restrict__ u, u16* __restrict__ xb,
                     u16* __restrict__ wpk){
  const int b = blockIdx.x;
  if (b < PREP_XBLKS){
    int t = b * 256 + threadIdx.x;
    int r = t >> 6, l = t & 63;
    int kk = r & 1, i = (r >> 1) & 3, h = (r >> 3) & 1, kt = (r >> 4) & 15, mb = r >> 8;
    int q = l >> 4, c = l & 15;
    int row = mb*128 + h*64 + i*16 + c;
    int k0  = kt*64 + kk*32 + q*8;
    const float* src = x + (size_t)row * IN_DIM + k0;
    float4 a0 = *reinterpret_cast<const float4*>(src);
    float4 a1 = *reinterpret_cast<const float4*>(src + 4);
    uint4 out;
    out.x = f2bf_pk(a0.x, a0.y); out.y = f2bf_pk(a0.z, a0.w);
    out.z = f2bf_pk(a1.x, a1.y); out.w = f2bf_pk(a1.z, a1.w);
    *reinterpret_cast<uint4*>(xb + (size_t)r*512 + l*8) = out;
  } else {
    int t = (b - PREP_XBLKS) * 256 + threadIdx.x;   // 131072 threads
    int r = t >> 6, l = t & 63;
    int kk = r & 1, j = (r >> 1) & 3, kt = (r >> 3) & 15, cs = r >> 7;
    int q = l >> 4, c = l & 15;
    int bcol = cs*4 + j;
    const float* src = (bcol & 1) ? u : v;
    int lcol = (bcol >> 1)*16 + c;
    int k0 = kt*64 + kk*32 + q*8;
    u32 o[4];
#pragma unroll
    for (int ii = 0; ii < 4; ++ii){
      float a  = src[(size_t)(k0 + 2*ii    ) * L_DIM + lcol];
      float bb = src[(size_t)(k0 + 2*ii + 1) * L_DIM + lcol];
      o[ii] = f2bf_pk(a, bb);
    }
    *reinterpret_cast<uint4*>(wpk + (size_t)r*512 + l*8) = make_uint4(o[0], o[1], o[2], o[3]);
  }
}

#define LOADA(KT, B_) { const u16* ak_ = awave + (size_t)(KT)*8192;                 \
  _Pragma("unroll") for (int gi_ = 0; gi_ < 4; ++gi_)                               \
    _Pragma("unroll") for (int kk_ = 0; kk_ < 2; ++kk_)                             \
      afb[B_][gi_][kk_] = *reinterpret_cast<const v8bf*>(ak_ + gi_*1024 + kk_*512); }

#define LOADB(KTL, B_) {                                                            \
  _Pragma("unroll") for (int j_ = 0; j_ < 4; ++j_)                                  \
    _Pragma("unroll") for (int kk_ = 0; kk_ < 2; ++kk_)                             \
      bfb[B_][j_][kk_] = *reinterpret_cast<const v8bf*>(&Bs[((KTL)*8 + j_*2 + kk_)*512 + lane*8]); }

#define DOMFMA(B_) {                                                                \
  _Pragma("unroll") for (int kk_ = 0; kk_ < 2; ++kk_)                               \
    _Pragma("unroll") for (int gi_ = 0; gi_ < 4; ++gi_)                             \
      _Pragma("unroll") for (int j_ = 0; j_ < 4; ++j_)                              \
        acc[gi_][j_] = __builtin_amdgcn_mfma_f32_16x16x32_bf16(                     \
            afb[B_][gi_][kk_], bfb[B_][j_][kk_], acc[gi_][j_], 0, 0, 0); }

__launch_bounds__(256, 2)
__global__ void gemm_score(const u16* __restrict__ xb, const u16* __restrict__ wpk,
                           const float* __restrict__ w, float* __restrict__ partial){
  // Block = 2 mblk x 64 pcols x full K. B in LDS per K-half (3 barriers total).
  // Register double-buffer: kt+1's A-globals + B-ds_reads in flight during kt's MFMA.
  __shared__ __align__(16) u16 Bs[64 * 512];   // 64 KB -> 2 blocks/CU

  const int tid  = threadIdx.x;
  const u32 bid  = blockIdx.x;          // 0..2047
  const int xcd  = bid & 7;
  const int slot = bid >> 3;            // 0..255
  const int cs   = slot & 15;
  const int mr   = xcd*16 + (slot >> 4);  // 0..127, XCD-local A reuse
  const int mblk0= mr * 2;

  const int lane = tid & 63;
  const int wave = tid >> 6;
  const int q    = lane >> 4;
  const int c    = lane & 15;

  auto stageB = [&](int kh){
    const u16* src = wpk + (size_t)(cs*128 + kh*64) * 512;
#pragma unroll
    for (int it = 0; it < 16; ++it){
      const int rl = wave*16 + it;
      gl2lds16(src + (size_t)rl*512 + lane*8, &Bs[rl*512 + lane*8]);
    }
  };

  // wave -> mblk (wave>>1), row-groups g = (wave&1)*4 .. +3
  const u16* awave = xb + (size_t)(mblk0 + (wave>>1))*131072
                        + (size_t)((wave&1)*4)*1024 + lane*8;

  v8bf afb[2][4][2];
  v8bf bfb[2][4][2];
  v4f  acc[4][4];
#pragma unroll
  for (int gi = 0; gi < 4; ++gi)
#pragma unroll
    for (int j = 0; j < 4; ++j)
      acc[gi][j] = (v4f){0.f, 0.f, 0.f, 0.f};

  stageB(0);
  LOADA(0, 0);
  __syncthreads();
  LOADB(0, 0);

  // K-half 0: kt = 0..7
#pragma unroll 1
  for (int k2 = 0; k2 < 4; ++k2){
    const int kt = 2*k2;
    LOADA(kt+1, 1); LOADB(2*k2+1, 1);
    DOMFMA(0);
    LOADA(kt+2, 0);                      // kt+2 = 2..8 (8 = first of half 1)
    if (k2 < 3) LOADB(2*k2+2, 0);
    DOMFMA(1);
  }
  __syncthreads();     // all waves done reading Bs half 0
  stageB(1);
  __syncthreads();     // half 1 visible
  LOADB(0, 0);

  // K-half 1: kt = 8..15 (A for kt=8 already in afb[0])
#pragma unroll 1
  for (int k2 = 0; k2 < 4; ++k2){
    const int kt = 8 + 2*k2;
    LOADA(kt+1, 1); LOADB(2*k2+1, 1);
    DOMFMA(0);
    if (k2 < 3){ LOADA(kt+2, 0); LOADB(2*k2+2, 0); }
    DOMFMA(1);
  }

  // epilogue: j pairs (0,1)=V,U @ l=cs*32+c ; (2,3)=V,U @ +16
  const float wl0 = w[cs*32 + c];
  const float wl1 = w[cs*32 + 16 + c];
  float* pout = partial + (size_t)cs * M_TOT
              + (size_t)(mblk0 + (wave>>1))*128 + (wave&1)*64;

#pragma unroll
  for (int gi = 0; gi < 4; ++gi){
#pragma unroll
    for (int r = 0; r < 4; ++r){
      float t0 = 2.f / (1.f + __expf(-2.f * acc[gi][0][r])) - 1.f;
      float s0 = 1.f / (1.f + __expf(-acc[gi][1][r]));
      float t1 = 2.f / (1.f + __expf(-2.f * acc[gi][2][r])) - 1.f;
      float s1 = 1.f / (1.f + __expf(-acc[gi][3][r]));
      float v2 = t0*s0*wl0 + t1*s1*wl1;
      v2 += __shfl_xor(v2, 1, 64);
      v2 += __shfl_xor(v2, 2, 64);
      v2 += __shfl_xor(v2, 4, 64);
      v2 += __shfl_xor(v2, 8, 64);
      if (c == 0) pout[gi*16 + q*4 + r] = v2;   // slice-private rows
    }
  }
}

__global__ void softmax_inst(const float* __restrict__ partial, float* __restrict__ out){
  __shared__ float red[N_INST];
  const int b = blockIdx.x;
  const int n = threadIdx.x;
  float s = 0.f;
#pragma unroll
  for (int i = 0; i < NSLICE; ++i) s += partial[(size_t)i * M_TOT + n*BATCH + b];
  red[n] = s; __syncthreads();
  for (int st = N_INST/2; st > 0; st >>= 1){
    if (n < st) red[n] = fmaxf(red[n], red[n + st]);
    __syncthreads();
  }
  float mx = red[0]; __syncthreads();
  float e = __expf(s - mx);
  red[n] = e; __syncthreads();
  for (int st = N_INST/2; st > 0; st >>= 1){
    if (n < st) red[n] += red[n + st];
    __syncthreads();
  }
  out[n*BATCH + b] = e / red[0];
}

extern "C" void kernel_launch(void* const* d_in, const int* in_sizes, int n_in,
                              void* d_out, int out_size, void* d_ws, size_t ws_size,
                              hipStream_t stream) {
  const float* x = (const float*)d_in[0];
  const float* v = (const float*)d_in[1];
  const float* u = (const float*)d_in[2];
  const float* w = (const float*)d_in[3];
  u16*   xb      = (u16*)d_ws;
  u16*   wpk     = (u16*)((char*)d_ws + XB_BYTES);
  float* partial = (float*)((char*)d_ws + XB_BYTES + WPK_BYTES);
  float* out     = (float*)d_out;

  prep<<<dim3(PREP_XBLKS + 512), dim3(256), 0, stream>>>(x, v, u, xb, wpk);
  gemm_score<<<dim3(2048), dim3(256), 0, stream>>>(xb, wpk, w, partial);
  softmax_inst<<<dim3(BATCH), dim3(N_INST), 0, stream>>>(partial, out);
}